// Round 10
// baseline (223.915 us; speedup 1.0000x reference)
//
#include <hip/hip_runtime.h>
#include <hip/hip_bf16.h>

// GraphConvolution: agg[i] = weighted-mean over edges with src=i of feat[dst]; out = relu(agg @ W + b)
// N=50000, E=1600000, D=U=128, fp32 in/out.
//
// R10: finB now sorts into a 47KB LDS paybuf (zero-init -> free zero-weight pads) and writes
// pay4 with one coalesced uint4 linear copy. Rationale: R4 measured scattered partial-line
// stores cost a full 64B line transaction each (fill: WRITE_SIZE = E*64B); R9's finB scatter
// phase had exactly that pattern (1.6M random 4B global stores). All other kernels unchanged:
// histA (cvt prologue + per-block 196-superbucket hist), scanB (1 wave/bucket), scatterC
// (16-edge/128B dense sub-segments), agg (8 gathers in flight, zero LDS), gemm (mfma bf16).

typedef unsigned int vuint4 __attribute__((ext_vector_type(4)));
typedef short bf16x8 __attribute__((ext_vector_type(8)));
typedef float f32x4 __attribute__((ext_vector_type(4)));

#define SRCSH 8                 // superbucket = src >> 8 (256 nodes/bucket)
#define BNODES 256
#define BCAP 9728               // staging cap: mean 8163 edges/bucket, +17 sigma
#define PCAP 11776              // pay4 cap (uints): BCAP + 256*7 pads, x16B aligned
#define NBLK 512                // edge-chunk blocks for histA/scatterC

__device__ __forceinline__ unsigned short f2bf(float f) {
    unsigned u = __float_as_uint(f);
    unsigned r = (u + 0x7fff + ((u >> 16) & 1)) >> 16;   // RNE
    return (unsigned short)r;
}
__device__ __forceinline__ float bf2f(unsigned short h) {
    return __uint_as_float(((unsigned)h) << 16);
}

// histA: cvt prologue (feat->bf16, W->WT bf16) + per-block superbucket histogram.
__global__ __launch_bounds__(256)
void histA_kernel(const float* __restrict__ feat, ushort* __restrict__ featb,
                  const float* __restrict__ W, ushort* __restrict__ WT,
                  const int* __restrict__ esrc, int* __restrict__ cnt,
                  int E, int nbuk, int N, int D) {
    __shared__ int hcnt[256];
    int tid = threadIdx.x, blk = blockIdx.x;

    {   // prologue: conversions
        int gid = blk * 256 + tid;
        int gstr = NBLK * 256;
        int nf4 = N * D / 4;
        for (int i = gid; i < nf4; i += gstr) {
            float4 v = ((const float4*)feat)[i];
            ushort4 r;
            r.x = f2bf(v.x); r.y = f2bf(v.y); r.z = f2bf(v.z); r.w = f2bf(v.w);
            ((ushort4*)featb)[i] = r;
        }
        int nw = D * D;
        for (int i = gid; i < nw; i += gstr) {
            int u = i >> 7, k = i & 127;
            WT[i] = f2bf(W[k * 128 + u]);   // WT[u][k] = W[k][u]
        }
    }

    hcnt[tid] = 0;
    __syncthreads();

    int per = ((E + NBLK - 1) / NBLK + 3) & ~3;
    int lo = blk * per;
    int hi = lo + per; if (hi > E) hi = E;
    for (int i4 = (lo >> 2) + tid; i4 < (hi >> 2); i4 += 256) {
        int4 s = ((const int4*)esrc)[i4];
        atomicAdd(&hcnt[s.x >> SRCSH], 1);
        atomicAdd(&hcnt[s.y >> SRCSH], 1);
        atomicAdd(&hcnt[s.z >> SRCSH], 1);
        atomicAdd(&hcnt[s.w >> SRCSH], 1);
    }
    __syncthreads();
    if (tid < nbuk) cnt[blk * nbuk + tid] = hcnt[tid];
}

// scanB: one wave per superbucket; exclusive scan of cnt[0..511][b] -> hbase[b][0..511], gtot[b].
__global__ __launch_bounds__(256)
void scanB_kernel(const int* __restrict__ cnt, int* __restrict__ hbase,
                  int* __restrict__ gtot, int nbuk) {
    int lane = threadIdx.x & 63, wid = threadIdx.x >> 6;
    int b = blockIdx.x * 4 + wid;
    if (b >= nbuk) return;

    int v[8]; int run = 0;
    #pragma unroll
    for (int i = 0; i < 8; ++i) {                 // lane owns blk = lane*8 + i
        v[i] = cnt[(lane * 8 + i) * nbuk + b];
        run += v[i];
    }
    int x = run;
    #pragma unroll
    for (int off = 1; off < 64; off <<= 1) {
        int y = __shfl_up(x, off, 64);
        if (lane >= off) x += y;
    }
    int excl = x - run;
    #pragma unroll
    for (int i = 0; i < 8; ++i) {
        hbase[b * NBLK + lane * 8 + i] = excl;
        excl += v[i];
    }
    if (lane == 63) gtot[b] = x;
}

// scatterC: scatter packed (w_fp32<<32 | src8<<16 | dst16) into dense per-(block,bucket)
// sub-segments (~16 edges = 128B each). LDS cursors only.
__global__ __launch_bounds__(256)
void scatterC_kernel(const int* __restrict__ esrc, const int* __restrict__ edst,
                     const float* __restrict__ ew, const int* __restrict__ hbase,
                     unsigned long long* __restrict__ staging, int E, int nbuk) {
    __shared__ int hb[256];
    __shared__ int hoff[256];
    int tid = threadIdx.x, blk = blockIdx.x;
    if (tid < nbuk) { hb[tid] = hbase[tid * NBLK + blk]; }
    hoff[tid] = 0;
    __syncthreads();

    int per = ((E + NBLK - 1) / NBLK + 3) & ~3;
    int lo = blk * per;
    int hi = lo + per; if (hi > E) hi = E;
    for (int i4 = (lo >> 2) + tid; i4 < (hi >> 2); i4 += 256) {
        int4 s = ((const int4*)esrc)[i4];
        int4 d = ((const int4*)edst)[i4];
        float4 w = ((const float4*)ew)[i4];
        #pragma unroll
        for (int k = 0; k < 4; ++k) {
            int sv = (k == 0) ? s.x : (k == 1) ? s.y : (k == 2) ? s.z : s.w;
            int dv = (k == 0) ? d.x : (k == 1) ? d.y : (k == 2) ? d.z : d.w;
            float wv = (k == 0) ? w.x : (k == 1) ? w.y : (k == 2) ? w.z : w.w;
            int b = sv >> SRCSH;
            int pos = hb[b] + atomicAdd(&hoff[b], 1);
            if (pos < BCAP) {
                unsigned long long v = ((unsigned long long)__float_as_uint(wv) << 32)
                                     | ((unsigned long long)(sv & (BNODES - 1)) << 16)
                                     | (unsigned long long)(unsigned)dv;
                staging[(size_t)b * BCAP + pos] = v;
            }
        }
    }
}

// finB: one block per superbucket (256 nodes, ~8200 edges). Hist 256 local srcs, padded
// 256-thread scan, sort 4B payloads (w_bf16<<16|dst16) into zero-initialized LDS paybuf
// (pads = untouched zeros), then ONE coalesced uint4 linear copy LDS -> pay4.
__global__ __launch_bounds__(256)
void finB_kernel(const int* __restrict__ gtot, const unsigned long long* __restrict__ staging,
                 unsigned* __restrict__ pay4, int* __restrict__ rs, int* __restrict__ re, int N) {
    __shared__ unsigned paybuf[PCAP];   // 47 KB
    __shared__ int hist[BNODES];
    __shared__ int hcur[BNODES];
    __shared__ int ws[4];
    __shared__ int stotal;
    int b = blockIdx.x, tid = threadIdx.x;

    for (int i = tid; i < PCAP / 4; i += 256) ((vuint4*)paybuf)[i] = (vuint4){0, 0, 0, 0};
    hist[tid] = 0;
    __syncthreads();

    int m = gtot[b]; if (m > BCAP) m = BCAP;
    size_t sbase = (size_t)b * BCAP;
    for (int i = tid; i < m; i += 256) {
        unsigned long long v = staging[sbase + i];
        atomicAdd(&hist[(int)((v >> 16) & (BNODES - 1))], 1);
    }
    __syncthreads();

    // 256-thread exclusive scan of x8-padded counts
    int lane = tid & 63, wid = tid >> 6;
    int h = hist[tid];
    int p = (h + 7) & ~7;
    int x = p;
    #pragma unroll
    for (int off = 1; off < 64; off <<= 1) {
        int y = __shfl_up(x, off, 64);
        if (lane >= off) x += y;
    }
    if (lane == 63) ws[wid] = x;
    __syncthreads();
    if (tid == 0) { int a = 0; for (int w = 0; w < 4; ++w) { int t = ws[w]; ws[w] = a; a += t; } }
    __syncthreads();
    int excl = ws[wid] + x - p;

    int gb = b * PCAP;
    hcur[tid] = excl;
    int n = b * BNODES + tid;
    if (n < N) { rs[n] = gb + excl; re[n] = gb + excl + p; }
    if (tid == 255) stotal = excl + p;   // total padded length, multiple of 8
    __syncthreads();

    for (int i = tid; i < m; i += 256) {
        unsigned long long v = staging[sbase + i];   // L2-hot second read
        int s8 = (int)((v >> 16) & (BNODES - 1));
        int pos = atomicAdd(&hcur[s8], 1);
        unsigned wbf = f2bf(__uint_as_float((unsigned)(v >> 32)));
        paybuf[pos] = (wbf << 16) | (unsigned)(v & 0xffffu);
    }
    __syncthreads();

    int t4 = stotal >> 2;                 // uint4 count (stotal % 8 == 0)
    vuint4* dst = (vuint4*)(pay4 + gb);   // gb*4 % 16 == 0
    for (int i = tid; i < t4; i += 256)
        dst[i] = ((const vuint4*)paybuf)[i];   // coalesced streaming write
}

// One wave per 4 nodes, zero LDS. Lane owns features (2L,2L+1). Segments are x8-padded:
// two uint4 payload loads + 8 gathers in flight, no tail masking.
__global__ __launch_bounds__(256, 8)
void agg_kernel(const ushort* __restrict__ featb, const unsigned* __restrict__ pay4,
                const int* __restrict__ rs, const int* __restrict__ re,
                ushort* __restrict__ aggb, int N) {
    int tid = threadIdx.x, lane = tid & 63, wid = tid >> 6;
    const ushort2* feat2 = (const ushort2*)featb;
    ushort2* agg2 = (ushort2*)aggb;

    int n0 = (blockIdx.x * 4 + wid) * 4;
    #pragma unroll
    for (int j = 0; j < 4; ++j) {
        int n = n0 + j;
        if (n >= N) break;
        int p = rs[n], pend = re[n];
        float ax = 0.f, ay = 0.f, ws = 0.f;
        for (; p < pend; p += 8) {
            vuint4 qa = __builtin_nontemporal_load((const vuint4*)(pay4 + p));
            vuint4 qb = __builtin_nontemporal_load((const vuint4*)(pay4 + p + 4));
            unsigned q[8] = {qa.x, qa.y, qa.z, qa.w, qb.x, qb.y, qb.z, qb.w};
            ushort2 f[8];
            #pragma unroll
            for (int k = 0; k < 8; ++k)
                f[k] = feat2[(q[k] & 0xffffu) * 64 + lane];   // 8 coalesced 256B-row gathers
            #pragma unroll
            for (int k = 0; k < 8; ++k) {
                float w = bf2f((unsigned short)(q[k] >> 16));  // pads have w=0
                ax += w * bf2f(f[k].x);
                ay += w * bf2f(f[k].y);
                ws += w;
            }
        }
        float inv = 1.f / fmaxf(ws, 1e-12f);
        ushort2 o;
        o.x = f2bf(ax * inv);
        o.y = f2bf(ay * inv);
        agg2[(size_t)n * 64 + lane] = o;   // L2-resident for gemm
    }
}

// out = relu(agg @ W + b) via mfma_f32_16x16x32_bf16. One wave per 16-row tile.
__global__ __launch_bounds__(256)
void gemm_kernel(const ushort* __restrict__ aggb, const ushort* __restrict__ WT,
                 const float* __restrict__ bias, float* __restrict__ out, int ntiles) {
    int tid = threadIdx.x, lane = tid & 63, wid = tid >> 6;
    int tile = blockIdx.x * 4 + wid;
    if (tile >= ntiles) return;
    int m = lane & 15, quad = lane >> 4;

    f32x4 acc[8];
    #pragma unroll
    for (int t = 0; t < 8; ++t) acc[t] = (f32x4){0.f, 0.f, 0.f, 0.f};

    #pragma unroll
    for (int ks = 0; ks < 4; ++ks) {
        bf16x8 a = *(const bf16x8*)(aggb + ((size_t)(tile * 16 + m) * 128 + ks * 32 + quad * 8));
        #pragma unroll
        for (int nt = 0; nt < 8; ++nt) {
            bf16x8 bfr = *(const bf16x8*)(WT + ((nt * 16 + m) * 128 + ks * 32 + quad * 8));
            acc[nt] = __builtin_amdgcn_mfma_f32_16x16x32_bf16(a, bfr, acc[nt], 0, 0, 0);
        }
    }

    #pragma unroll
    for (int nt = 0; nt < 8; ++nt) {
        int col = nt * 16 + m;
        float bv = bias[col];
        #pragma unroll
        for (int r = 0; r < 4; ++r) {
            int row = tile * 16 + quad * 4 + r;
            float v = fmaxf(acc[nt][r] + bv, 0.f);
            __builtin_nontemporal_store(v, out + (size_t)row * 128 + col);
        }
    }
}

extern "C" void kernel_launch(void* const* d_in, const int* in_sizes, int n_in,
                              void* d_out, int out_size, void* d_ws, size_t ws_size,
                              hipStream_t stream) {
    const float* feat = (const float*)d_in[0];
    const int*   esrc = (const int*)d_in[1];
    const int*   edst = (const int*)d_in[2];
    const float* ew   = (const float*)d_in[3];
    const float* W    = (const float*)d_in[4];
    const float* bias = (const float*)d_in[5];
    float* out = (float*)d_out;

    const int D = 128;
    int N = in_sizes[0] / D;                // 50000
    int E = in_sizes[1];                    // 1600000
    int nbuk = (N + BNODES - 1) >> SRCSH;   // 196

    // ws: staging u64[nbuk*BCAP] (15.3 MB) | cnt[NBLK*nbuk] | hbase[nbuk*NBLK] | gtot[nbuk] |
    //     rs[N] | re[N] | pay4 u32[nbuk*PCAP] (9.2 MB) | featb | aggb | WT   (~51.5 MB)
    unsigned long long* staging = (unsigned long long*)d_ws;
    int* cnt   = (int*)(staging + (size_t)nbuk * BCAP);
    int* hbase = cnt + (size_t)NBLK * nbuk;
    int* gtot  = hbase + (size_t)nbuk * NBLK;
    int* rs    = gtot + nbuk;
    int* re    = rs + N;
    unsigned* pay4 = (unsigned*)(re + N);
    ushort* featb = (ushort*)(pay4 + (size_t)nbuk * PCAP);
    ushort* aggb  = featb + (size_t)N * D;
    ushort* WT    = aggb + (size_t)N * D;

    histA_kernel<<<NBLK, 256, 0, stream>>>(feat, featb, W, WT, esrc, cnt, E, nbuk, N, D);
    scanB_kernel<<<(nbuk + 3) / 4, 256, 0, stream>>>(cnt, hbase, gtot, nbuk);
    scatterC_kernel<<<NBLK, 256, 0, stream>>>(esrc, edst, ew, hbase, staging, E, nbuk);
    finB_kernel<<<nbuk, 256, 0, stream>>>(gtot, staging, pay4, rs, re, N);
    agg_kernel<<<N / 16, 256, 0, stream>>>(featb, pay4, rs, re, aggb, N);
    int ntiles = N / 16;
    gemm_kernel<<<(ntiles + 3) / 4, 256, 0, stream>>>(aggb, WT, bias, out, ntiles);
}